// Round 1
// baseline (553.530 us; speedup 1.0000x reference)
//
#include <hip/hip_runtime.h>

#define Bb 16
#define Nn 512
#define Ee 512
#define Hh 8
#define Dd 64
constexpr int Mm = Bb * Nn;  // 8192

// ---------------------------------------------------------------------------
// GEMM: C[m,e] = sum_k X[m,k] * W[e,k] + bias[e]
// X row-major [M,512], W row-major [E,512] (so this is X @ W^T).
// MODE 0: scatter into [B,H,N,D] layout (for q/k/v, head-major)
// MODE 1: plain row-major [M,E] (final output projection)
// 64x64 tile, BK=16, 256 threads, 4x4 per thread, fp32.
// ---------------------------------------------------------------------------
template <int MODE>
__global__ __launch_bounds__(256) void gemm_kernel(const float* __restrict__ X,
                                                   const float* __restrict__ W,
                                                   const float* __restrict__ bias,
                                                   float* __restrict__ out) {
    constexpr int K = 512;
    __shared__ float Xs[16][64 + 1];
    __shared__ float Ws[16][64 + 1];
    const int tid = threadIdx.x;
    const int tx = tid & 15, ty = tid >> 4;
    const int m0 = blockIdx.x * 64;
    const int e0 = blockIdx.y * 64;

    float acc[4][4] = {};

    for (int k0 = 0; k0 < K; k0 += 16) {
#pragma unroll
        for (int t = 0; t < 4; ++t) {
            int idx = tid + t * 256;
            int r = idx >> 4;    // 0..63
            int kk = idx & 15;   // 0..15
            Xs[kk][r] = X[(size_t)(m0 + r) * K + k0 + kk];
            Ws[kk][r] = W[(size_t)(e0 + r) * K + k0 + kk];
        }
        __syncthreads();
#pragma unroll
        for (int kk = 0; kk < 16; ++kk) {
            float a[4], bv[4];
#pragma unroll
            for (int i = 0; i < 4; ++i) a[i] = Xs[kk][ty * 4 + i];
#pragma unroll
            for (int j = 0; j < 4; ++j) bv[j] = Ws[kk][tx * 4 + j];
#pragma unroll
            for (int i = 0; i < 4; ++i)
#pragma unroll
                for (int j = 0; j < 4; ++j) acc[i][j] += a[i] * bv[j];
        }
        __syncthreads();
    }

#pragma unroll
    for (int i = 0; i < 4; ++i) {
        int m = m0 + ty * 4 + i;
#pragma unroll
        for (int j = 0; j < 4; ++j) {
            int e = e0 + tx * 4 + j;
            float c = acc[i][j] + bias[e];
            if (MODE == 0) {
                int b = m >> 9;        // m / N
                int n = m & 511;       // m % N
                int h = e >> 6;        // e / D
                int d = e & 63;        // e % D
                out[(((size_t)b * Hh + h) * Nn + n) * Dd + d] = c;
            } else {
                out[(size_t)m * Ee + e] = c;
            }
        }
    }
}

// ---------------------------------------------------------------------------
// Flash-style attention. Block = 256 threads handles one (b, h, 64-query tile).
// Online softmax, K/V/P staged in LDS, fp32 throughout.
// ---------------------------------------------------------------------------
__global__ __launch_bounds__(256) void attn_kernel(const float* __restrict__ q,
                                                   const float* __restrict__ k,
                                                   const float* __restrict__ v,
                                                   const float* __restrict__ db,
                                                   const int* __restrict__ mask,
                                                   float* __restrict__ o) {
    __shared__ float Qs[64][65];
    __shared__ float Ks[64][65];
    __shared__ float Vs[64][65];
    __shared__ float Ps[64][65];

    const int tid = threadIdx.x;
    const int tx = tid & 15, ty = tid >> 4;
    const int i0 = blockIdx.x * 64;
    const int h = blockIdx.y;
    const int b = blockIdx.z;
    const float scale = 0.125f;  // 1/sqrt(64)

    const float* qbh = q + (((size_t)b * Hh + h) * Nn) * Dd;
    const float* kbh = k + (((size_t)b * Hh + h) * Nn) * Dd;
    const float* vbh = v + (((size_t)b * Hh + h) * Nn) * Dd;

    // Load Q tile [64][64]
#pragma unroll
    for (int t = 0; t < 16; ++t) {
        int idx = tid + t * 256;
        int r = idx >> 6, d = idx & 63;
        Qs[r][d] = qbh[(size_t)(i0 + r) * Dd + d];
    }

    float m_run[4], l_run[4], o_acc[4][4];
#pragma unroll
    for (int i = 0; i < 4; ++i) {
        m_run[i] = -1e30f;
        l_run[i] = 0.f;
#pragma unroll
        for (int j = 0; j < 4; ++j) o_acc[i][j] = 0.f;
    }

    for (int j0 = 0; j0 < Nn; j0 += 64) {
        // Load K,V tiles
#pragma unroll
        for (int t = 0; t < 16; ++t) {
            int idx = tid + t * 256;
            int r = idx >> 6, d = idx & 63;
            Ks[r][d] = kbh[(size_t)(j0 + r) * Dd + d];
            Vs[r][d] = vbh[(size_t)(j0 + r) * Dd + d];
        }
        __syncthreads();  // K,V (and Q on first iter) visible

        // S = Q K^T, 4x4 per thread
        float s[4][4] = {};
#pragma unroll
        for (int dd = 0; dd < 64; ++dd) {
            float a[4], bv[4];
#pragma unroll
            for (int i = 0; i < 4; ++i) a[i] = Qs[ty * 4 + i][dd];
#pragma unroll
            for (int j = 0; j < 4; ++j) bv[j] = Ks[tx * 4 + j][dd];
#pragma unroll
            for (int i = 0; i < 4; ++i)
#pragma unroll
                for (int j = 0; j < 4; ++j) s[i][j] += a[i] * bv[j];
        }

        // scale + db + clip + mask
#pragma unroll
        for (int i = 0; i < 4; ++i) {
            int gi = i0 + ty * 4 + i;
#pragma unroll
            for (int j = 0; j < 4; ++j) {
                int gj = j0 + tx * 4 + j;
                float val = s[i][j] * scale + db[((size_t)b * Nn + gi) * Nn + gj];
                val = fminf(fmaxf(val, -10.f), 10.f);
                if (mask[b * Nn + gj] == 0) val = -1e9f;
                s[i][j] = val;
            }
        }

        // online softmax per row (reduce across 16 tx lanes within wave)
#pragma unroll
        for (int i = 0; i < 4; ++i) {
            float rmax = fmaxf(fmaxf(s[i][0], s[i][1]), fmaxf(s[i][2], s[i][3]));
#pragma unroll
            for (int off = 1; off < 16; off <<= 1)
                rmax = fmaxf(rmax, __shfl_xor(rmax, off));
            float mo = m_run[i];
            float mn = fmaxf(mo, rmax);
            float corr = __expf(mo - mn);
            float rsum = 0.f;
#pragma unroll
            for (int j = 0; j < 4; ++j) {
                s[i][j] = __expf(s[i][j] - mn);
                rsum += s[i][j];
            }
#pragma unroll
            for (int off = 1; off < 16; off <<= 1) rsum += __shfl_xor(rsum, off);
            m_run[i] = mn;
            l_run[i] = l_run[i] * corr + rsum;
#pragma unroll
            for (int j = 0; j < 4; ++j) o_acc[i][j] *= corr;
        }

        // write P to LDS
#pragma unroll
        for (int i = 0; i < 4; ++i)
#pragma unroll
            for (int j = 0; j < 4; ++j) Ps[ty * 4 + i][tx * 4 + j] = s[i][j];
        __syncthreads();  // P ready

        // O += P V
#pragma unroll
        for (int jj = 0; jj < 64; ++jj) {
            float a[4], bv[4];
#pragma unroll
            for (int i = 0; i < 4; ++i) a[i] = Ps[ty * 4 + i][jj];
#pragma unroll
            for (int j = 0; j < 4; ++j) bv[j] = Vs[jj][tx * 4 + j];
#pragma unroll
            for (int i = 0; i < 4; ++i)
#pragma unroll
                for (int j = 0; j < 4; ++j) o_acc[i][j] += a[i] * bv[j];
        }
        __syncthreads();  // done reading Vs/Ps before next tile overwrites
    }

    // epilogue: normalize and write [B,N,E] (e = h*64 + d)
#pragma unroll
    for (int i = 0; i < 4; ++i) {
        int gi = i0 + ty * 4 + i;
        float inv = 1.f / l_run[i];
#pragma unroll
        for (int j = 0; j < 4; ++j) {
            o[((size_t)b * Nn + gi) * Ee + h * Dd + tx * 4 + j] = o_acc[i][j] * inv;
        }
    }
}

extern "C" void kernel_launch(void* const* d_in, const int* in_sizes, int n_in,
                              void* d_out, int out_size, void* d_ws, size_t ws_size,
                              hipStream_t stream) {
    const float* x   = (const float*)d_in[0];
    const float* db  = (const float*)d_in[1];
    const int*   msk = (const int*)d_in[2];
    const float* wq  = (const float*)d_in[3];
    const float* bq  = (const float*)d_in[4];
    const float* wk  = (const float*)d_in[5];
    const float* bk  = (const float*)d_in[6];
    const float* wv  = (const float*)d_in[7];
    const float* bv  = (const float*)d_in[8];
    const float* wo  = (const float*)d_in[9];
    const float* bo  = (const float*)d_in[10];
    float* out = (float*)d_out;

    const size_t per = (size_t)Bb * Hh * Nn * Dd;  // 4,194,304 floats
    float* q = (float*)d_ws;
    float* k = q + per;
    float* v = k + per;
    float* o = v + per;

    dim3 ggrid(Mm / 64, Ee / 64);
    gemm_kernel<0><<<ggrid, 256, 0, stream>>>(x, wq, bq, q);
    gemm_kernel<0><<<ggrid, 256, 0, stream>>>(x, wk, bk, k);
    gemm_kernel<0><<<ggrid, 256, 0, stream>>>(x, wv, bv, v);

    attn_kernel<<<dim3(Nn / 64, Hh, Bb), 256, 0, stream>>>(q, k, v, db, msk, o);

    gemm_kernel<1><<<ggrid, 256, 0, stream>>>(o, wo, bo, out);
}

// Round 2
// 117.905 us; speedup vs baseline: 4.6947x; 4.6947x over previous
//
#include <hip/hip_runtime.h>

typedef __attribute__((ext_vector_type(8))) short short8;
typedef __attribute__((ext_vector_type(4))) float f32x4;

#define MFMA16(A, B, C) __builtin_amdgcn_mfma_f32_16x16x32_bf16(A, B, C, 0, 0, 0)

__device__ __forceinline__ short f2bf(float f) {
    union { float f; unsigned u; } v;
    v.f = f;
    unsigned r = (v.u + 0x7FFFu + ((v.u >> 16) & 1u)) >> 16;
    return (short)r;
}

// ---------------------------------------------------------------------------
// fp32 -> bf16 conversion for x and the 4 weight matrices. 8 elems/thread.
// x: 4,194,304 elems (524288 units); each w: 262,144 (32768 units).
// ---------------------------------------------------------------------------
__global__ __launch_bounds__(256) void cvt_kernel(
    const float* __restrict__ x, const float* __restrict__ wq,
    const float* __restrict__ wk, const float* __restrict__ wv,
    const float* __restrict__ wo, short* __restrict__ xb,
    short* __restrict__ wqb, short* __restrict__ wkb,
    short* __restrict__ wvb, short* __restrict__ wob) {
    int i = blockIdx.x * 256 + threadIdx.x;
    const float* src;
    short* dst;
    int off;
    if (i < 524288) {
        src = x; dst = xb; off = i;
    } else {
        int j = i - 524288;
        int w = j >> 15;
        off = j & 32767;
        src = (w == 0) ? wq : (w == 1) ? wk : (w == 2) ? wv : wo;
        dst = (w == 0) ? wqb : (w == 1) ? wkb : (w == 2) ? wvb : wob;
    }
    const float* p = src + (size_t)off * 8;
    short8 r;
#pragma unroll
    for (int t = 0; t < 8; ++t) r[t] = f2bf(p[t]);
    *(short8*)(dst + (size_t)off * 8) = r;
}

// ---------------------------------------------------------------------------
// MFMA GEMM core: C[m,e] = sum_k A[m,k] * W[e,k], A [8192][512] bf16,
// W [512][512] bf16, 64x64 tile, BK=64, 256 thr (4 waves, 2x2 of 32x32).
// LDS padded +8 bf16 per row -> 2-way bank conflicts (free).
// ---------------------------------------------------------------------------
__device__ __forceinline__ void gemm_core(const short* __restrict__ A,
                                          const short* __restrict__ W,
                                          f32x4 acc[2][2], short* As, short* Bs,
                                          int m0, int e0) {
    const int tid = threadIdx.x, lane = tid & 63, wid = tid >> 6;
    const int c = lane & 15, g = lane >> 4;
    const int wr = (wid >> 1) * 32, wc = (wid & 1) * 32;

    short8 pa[2], pb[2];
#pragma unroll
    for (int p = 0; p < 2; ++p) {
        int s = p * 256 + tid;
        int row = s >> 3, c8 = s & 7;
        pa[p] = *(const short8*)&A[(size_t)(m0 + row) * 512 + c8 * 8];
        pb[p] = *(const short8*)&W[(size_t)(e0 + row) * 512 + c8 * 8];
    }
    for (int it = 0; it < 8; ++it) {
        __syncthreads();
#pragma unroll
        for (int p = 0; p < 2; ++p) {
            int s = p * 256 + tid;
            int row = s >> 3, c8 = s & 7;
            *(short8*)&As[row * 72 + c8 * 8] = pa[p];
            *(short8*)&Bs[row * 72 + c8 * 8] = pb[p];
        }
        if (it < 7) {
            int k0 = (it + 1) * 64;
#pragma unroll
            for (int p = 0; p < 2; ++p) {
                int s = p * 256 + tid;
                int row = s >> 3, c8 = s & 7;
                pa[p] = *(const short8*)&A[(size_t)(m0 + row) * 512 + k0 + c8 * 8];
                pb[p] = *(const short8*)&W[(size_t)(e0 + row) * 512 + k0 + c8 * 8];
            }
        }
        __syncthreads();
#pragma unroll
        for (int ks = 0; ks < 2; ++ks) {
            short8 af[2], bf[2];
#pragma unroll
            for (int mt = 0; mt < 2; ++mt)
                af[mt] = *(const short8*)&As[(wr + mt * 16 + c) * 72 + ks * 32 + g * 8];
#pragma unroll
            for (int nt = 0; nt < 2; ++nt)
                bf[nt] = *(const short8*)&Bs[(wc + nt * 16 + c) * 72 + ks * 32 + g * 8];
#pragma unroll
            for (int mt = 0; mt < 2; ++mt)
#pragma unroll
                for (int nt = 0; nt < 2; ++nt)
                    acc[mt][nt] = MFMA16(af[mt], bf[nt], acc[mt][nt]);
        }
    }
}

// QKV projection: grid (M/64, E/64, 3); z: 0=Q, 1=K, 2=V(transposed layout).
__global__ __launch_bounds__(256) void qkv_gemm(
    const short* __restrict__ xb, const short* __restrict__ wqb,
    const short* __restrict__ wkb, const short* __restrict__ wvb,
    const float* __restrict__ bq, const float* __restrict__ bk,
    const float* __restrict__ bvv, short* __restrict__ qo,
    short* __restrict__ ko, short* __restrict__ vto) {
    __shared__ short As[64 * 72];
    __shared__ short Bs[64 * 72];
    const int z = blockIdx.z;
    const short* W = (z == 0) ? wqb : (z == 1) ? wkb : wvb;
    const float* bias = (z == 0) ? bq : (z == 1) ? bk : bvv;
    short* out = (z == 0) ? qo : (z == 1) ? ko : vto;
    const int m0 = blockIdx.x * 64, e0 = blockIdx.y * 64;

    const f32x4 Z = {0.f, 0.f, 0.f, 0.f};
    f32x4 acc[2][2];
#pragma unroll
    for (int i = 0; i < 2; ++i)
#pragma unroll
        for (int j = 0; j < 2; ++j) acc[i][j] = Z;

    gemm_core(xb, W, acc, As, Bs, m0, e0);

    const int lane = threadIdx.x & 63, wid = threadIdx.x >> 6;
    const int c = lane & 15, g = lane >> 4;
    const int wr = (wid >> 1) * 32, wc = (wid & 1) * 32;
#pragma unroll
    for (int nt = 0; nt < 2; ++nt) {
        int e = e0 + wc + nt * 16 + c;
        float bsv = bias[e];
        int h = e >> 6, d = e & 63;
#pragma unroll
        for (int mt = 0; mt < 2; ++mt)
#pragma unroll
            for (int r = 0; r < 4; ++r) {
                int m = m0 + wr + mt * 16 + g * 4 + r;
                int bb = m >> 9, n = m & 511;
                float val = acc[mt][nt][r] + bsv;
                size_t addr;
                if (z == 2) addr = (((size_t)bb * 8 + h) * 64 + d) * 512 + n;
                else        addr = (((size_t)bb * 8 + h) * 512 + n) * 64 + d;
                out[addr] = f2bf(val);
            }
    }
}

// Output projection: fp32 out = ob @ wo^T + bo.
__global__ __launch_bounds__(256) void out_gemm(const short* __restrict__ ob,
                                                const short* __restrict__ wob,
                                                const float* __restrict__ bo,
                                                float* __restrict__ out) {
    __shared__ short As[64 * 72];
    __shared__ short Bs[64 * 72];
    const int m0 = blockIdx.x * 64, e0 = blockIdx.y * 64;
    const f32x4 Z = {0.f, 0.f, 0.f, 0.f};
    f32x4 acc[2][2];
#pragma unroll
    for (int i = 0; i < 2; ++i)
#pragma unroll
        for (int j = 0; j < 2; ++j) acc[i][j] = Z;

    gemm_core(ob, wob, acc, As, Bs, m0, e0);

    const int lane = threadIdx.x & 63, wid = threadIdx.x >> 6;
    const int c = lane & 15, g = lane >> 4;
    const int wr = (wid >> 1) * 32, wc = (wid & 1) * 32;
#pragma unroll
    for (int nt = 0; nt < 2; ++nt) {
        int e = e0 + wc + nt * 16 + c;
        float bsv = bo[e];
#pragma unroll
        for (int mt = 0; mt < 2; ++mt)
#pragma unroll
            for (int r = 0; r < 4; ++r) {
                int m = m0 + wr + mt * 16 + g * 4 + r;
                out[(size_t)m * 512 + e] = acc[mt][nt][r] + bsv;
            }
    }
}

// ---------------------------------------------------------------------------
// MFMA flash attention. Block = (b, h, 64 q-rows); 4 waves, wave-private
// 16 q-rows; no barriers in the j-loop. Q/K/V^T frags direct from global
// (L2-resident), P through wave-private padded LDS strip.
// ---------------------------------------------------------------------------
__global__ __launch_bounds__(256) void attn_mfma(
    const short* __restrict__ q, const short* __restrict__ k,
    const short* __restrict__ vt, const float* __restrict__ db,
    const int* __restrict__ mask, short* __restrict__ o) {
    __shared__ short Pl[4][16 * 72];
    const int tid = threadIdx.x, lane = tid & 63, wid = tid >> 6;
    const int c = lane & 15, g = lane >> 4;
    const int i0 = blockIdx.x * 64;
    const int h = blockIdx.y, b = blockIdx.z;
    const int q0 = i0 + wid * 16;

    const short* qp = q + (((size_t)b * 8 + h) * 512) * 64;
    const short* kp = k + (((size_t)b * 8 + h) * 512) * 64;
    const short* vp = vt + (((size_t)b * 8 + h) * 64) * 512;
    const float* dbp = db + ((size_t)b * 512 + q0 + g * 4) * 512;
    const int* mp = mask + b * 512;

    short8 qf0 = *(const short8*)&qp[(q0 + c) * 64 + g * 8];
    short8 qf1 = *(const short8*)&qp[(q0 + c) * 64 + 32 + g * 8];

    float m_run[4], l_run[4], corr[4];
    const f32x4 Z = {0.f, 0.f, 0.f, 0.f};
    f32x4 oacc[4];
#pragma unroll
    for (int r = 0; r < 4; ++r) { m_run[r] = -1e30f; l_run[r] = 0.f; }
#pragma unroll
    for (int dt = 0; dt < 4; ++dt) oacc[dt] = Z;

    short* pl = &Pl[wid][0];

    for (int j0 = 0; j0 < 512; j0 += 64) {
        // S = Q K^T  (rows: this wave's 16 q; cols: 64 keys)
        f32x4 s[4];
#pragma unroll
        for (int nt = 0; nt < 4; ++nt) {
            short8 kf0 = *(const short8*)&kp[(j0 + nt * 16 + c) * 64 + g * 8];
            short8 kf1 = *(const short8*)&kp[(j0 + nt * 16 + c) * 64 + 32 + g * 8];
            f32x4 z = Z;
            z = MFMA16(qf0, kf0, z);
            z = MFMA16(qf1, kf1, z);
            s[nt] = z;
        }
        // scale + db + clip + mask  (C layout: col=c -> key, row=g*4+r -> q)
        float sv[4][4];
#pragma unroll
        for (int nt = 0; nt < 4; ++nt) {
            bool mk = mp[j0 + nt * 16 + c] != 0;
#pragma unroll
            for (int r = 0; r < 4; ++r) {
                float val = s[nt][r] * 0.125f + dbp[(size_t)r * 512 + j0 + nt * 16 + c];
                val = fminf(fmaxf(val, -10.f), 10.f);
                sv[nt][r] = mk ? val : -1e9f;
            }
        }
        // online softmax per q-row r (reduce across the 16 c-lanes)
        float pv[4][4];
#pragma unroll
        for (int r = 0; r < 4; ++r) {
            float mx = fmaxf(fmaxf(sv[0][r], sv[1][r]), fmaxf(sv[2][r], sv[3][r]));
#pragma unroll
            for (int off = 1; off < 16; off <<= 1) mx = fmaxf(mx, __shfl_xor(mx, off));
            float mn = fmaxf(m_run[r], mx);
            corr[r] = __expf(m_run[r] - mn);
            float rs = 0.f;
#pragma unroll
            for (int nt = 0; nt < 4; ++nt) {
                float p = __expf(sv[nt][r] - mn);
                pv[nt][r] = p;
                rs += p;
            }
#pragma unroll
            for (int off = 1; off < 16; off <<= 1) rs += __shfl_xor(rs, off);
            m_run[r] = mn;
            l_run[r] = l_run[r] * corr[r] + rs;
        }
        // rescale O
#pragma unroll
        for (int dt = 0; dt < 4; ++dt)
#pragma unroll
            for (int r = 0; r < 4; ++r) oacc[dt][r] *= corr[r];
        // P -> bf16 -> wave-private LDS strip (row stride 72 = 2-way free)
#pragma unroll
        for (int nt = 0; nt < 4; ++nt)
#pragma unroll
            for (int r = 0; r < 4; ++r)
                pl[(g * 4 + r) * 72 + nt * 16 + c] = f2bf(pv[nt][r]);
        asm volatile("s_waitcnt lgkmcnt(0)" ::: "memory");
        __builtin_amdgcn_sched_barrier(0);
        // P A-frags + V^T B-frags, O += P V
        short8 pf0 = *(const short8*)&pl[c * 72 + g * 8];
        short8 pf1 = *(const short8*)&pl[c * 72 + 32 + g * 8];
#pragma unroll
        for (int dt = 0; dt < 4; ++dt) {
            short8 vf0 = *(const short8*)&vp[(dt * 16 + c) * 512 + j0 + g * 8];
            short8 vf1 = *(const short8*)&vp[(dt * 16 + c) * 512 + j0 + 32 + g * 8];
            oacc[dt] = MFMA16(pf0, vf0, oacc[dt]);
            oacc[dt] = MFMA16(pf1, vf1, oacc[dt]);
        }
    }
    // epilogue: O /= l, write bf16 [M][E] for the output projection
#pragma unroll
    for (int r = 0; r < 4; ++r) {
        float inv = 1.f / l_run[r];
        int qg = q0 + g * 4 + r;
#pragma unroll
        for (int dt = 0; dt < 4; ++dt)
            o[((size_t)b * 512 + qg) * 512 + h * 64 + dt * 16 + c] =
                f2bf(oacc[dt][r] * inv);
    }
}

extern "C" void kernel_launch(void* const* d_in, const int* in_sizes, int n_in,
                              void* d_out, int out_size, void* d_ws, size_t ws_size,
                              hipStream_t stream) {
    const float* x  = (const float*)d_in[0];
    const float* db = (const float*)d_in[1];
    const int* msk  = (const int*)d_in[2];
    const float* wq = (const float*)d_in[3];
    const float* bq = (const float*)d_in[4];
    const float* wk = (const float*)d_in[5];
    const float* bk = (const float*)d_in[6];
    const float* wv = (const float*)d_in[7];
    const float* bv = (const float*)d_in[8];
    const float* wo = (const float*)d_in[9];
    const float* bo = (const float*)d_in[10];
    float* out = (float*)d_out;

    short* xb  = (short*)d_ws;            // 8192*512
    short* wqb = xb + 4194304;            // 512*512 each
    short* wkb = wqb + 262144;
    short* wvb = wkb + 262144;
    short* wob = wvb + 262144;
    short* qb  = wob + 262144;            // [B,H,N,D] bf16
    short* kb  = qb + 4194304;            // [B,H,N,D]
    short* vtb = kb + 4194304;            // [B,H,D,N]
    short* ob  = vtb + 4194304;           // [M,E] bf16 attention output

    cvt_kernel<<<2560, 256, 0, stream>>>(x, wq, wk, wv, wo, xb, wqb, wkb, wvb, wob);
    qkv_gemm<<<dim3(128, 8, 3), 256, 0, stream>>>(xb, wqb, wkb, wvb, bq, bk, bv,
                                                  qb, kb, vtb);
    attn_mfma<<<dim3(8, 8, 16), 256, 0, stream>>>(qb, kb, vtb, db, msk, ob);
    out_gemm<<<dim3(128, 8), 256, 0, stream>>>(ob, wob, bo, out);
}

// Round 3
// 117.641 us; speedup vs baseline: 4.7052x; 1.0022x over previous
//
#include <hip/hip_runtime.h>

typedef __attribute__((ext_vector_type(8))) short short8;
typedef __attribute__((ext_vector_type(4))) float f32x4;

#define MFMA16(A, B, C) __builtin_amdgcn_mfma_f32_16x16x32_bf16(A, B, C, 0, 0, 0)

__device__ __forceinline__ short f2bf(float f) {
    union { float f; unsigned u; } v;
    v.f = f;
    unsigned r = (v.u + 0x7FFFu + ((v.u >> 16) & 1u)) >> 16;
    return (short)r;
}

__device__ __forceinline__ float bf2f(unsigned short u) {
    union { unsigned u; float f; } v;
    v.u = ((unsigned)u) << 16;
    return v.f;
}

// ---------------------------------------------------------------------------
// fp32 -> bf16 conversion: x (524288 u), weights (131072 u), db (524288 u).
// 8 elems/thread. Launch with 2560 blocks (no db) or 4608 blocks (with db).
// ---------------------------------------------------------------------------
__global__ __launch_bounds__(256) void cvt_kernel(
    const float* __restrict__ x, const float* __restrict__ wq,
    const float* __restrict__ wk, const float* __restrict__ wv,
    const float* __restrict__ wo, const float* __restrict__ db,
    short* __restrict__ xb, short* __restrict__ wqb, short* __restrict__ wkb,
    short* __restrict__ wvb, short* __restrict__ wob, short* __restrict__ dbb) {
    int i = blockIdx.x * 256 + threadIdx.x;
    const float* src;
    short* dst;
    int off;
    if (i < 524288) {
        src = x; dst = xb; off = i;
    } else if (i < 655360) {
        int j = i - 524288;
        int w = j >> 15;
        off = j & 32767;
        src = (w == 0) ? wq : (w == 1) ? wk : (w == 2) ? wv : wo;
        dst = (w == 0) ? wqb : (w == 1) ? wkb : (w == 2) ? wvb : wob;
    } else {
        src = db; dst = dbb; off = i - 655360;
    }
    const float* p = src + (size_t)off * 8;
    short8 r;
#pragma unroll
    for (int t = 0; t < 8; ++t) r[t] = f2bf(p[t]);
    *(short8*)(dst + (size_t)off * 8) = r;
}

// ---------------------------------------------------------------------------
// MFMA GEMM core: 64x64 tile, BK=64, 256 thr (4 waves, 2x2 of 32x32).
// ---------------------------------------------------------------------------
__device__ __forceinline__ void gemm_core(const short* __restrict__ A,
                                          const short* __restrict__ W,
                                          f32x4 acc[2][2], short* As, short* Bs,
                                          int m0, int e0) {
    const int tid = threadIdx.x, lane = tid & 63, wid = tid >> 6;
    const int c = lane & 15, g = lane >> 4;
    const int wr = (wid >> 1) * 32, wc = (wid & 1) * 32;

    short8 pa[2], pb[2];
#pragma unroll
    for (int p = 0; p < 2; ++p) {
        int s = p * 256 + tid;
        int row = s >> 3, c8 = s & 7;
        pa[p] = *(const short8*)&A[(size_t)(m0 + row) * 512 + c8 * 8];
        pb[p] = *(const short8*)&W[(size_t)(e0 + row) * 512 + c8 * 8];
    }
    for (int it = 0; it < 8; ++it) {
        __syncthreads();
#pragma unroll
        for (int p = 0; p < 2; ++p) {
            int s = p * 256 + tid;
            int row = s >> 3, c8 = s & 7;
            *(short8*)&As[row * 72 + c8 * 8] = pa[p];
            *(short8*)&Bs[row * 72 + c8 * 8] = pb[p];
        }
        if (it < 7) {
            int k0 = (it + 1) * 64;
#pragma unroll
            for (int p = 0; p < 2; ++p) {
                int s = p * 256 + tid;
                int row = s >> 3, c8 = s & 7;
                pa[p] = *(const short8*)&A[(size_t)(m0 + row) * 512 + k0 + c8 * 8];
                pb[p] = *(const short8*)&W[(size_t)(e0 + row) * 512 + k0 + c8 * 8];
            }
        }
        __syncthreads();
#pragma unroll
        for (int ks = 0; ks < 2; ++ks) {
            short8 af[2], bf[2];
#pragma unroll
            for (int mt = 0; mt < 2; ++mt)
                af[mt] = *(const short8*)&As[(wr + mt * 16 + c) * 72 + ks * 32 + g * 8];
#pragma unroll
            for (int nt = 0; nt < 2; ++nt)
                bf[nt] = *(const short8*)&Bs[(wc + nt * 16 + c) * 72 + ks * 32 + g * 8];
#pragma unroll
            for (int mt = 0; mt < 2; ++mt)
#pragma unroll
                for (int nt = 0; nt < 2; ++nt)
                    acc[mt][nt] = MFMA16(af[mt], bf[nt], acc[mt][nt]);
        }
    }
}

// QKV projection: grid (M/64, E/64, 3); z: 0=Q, 1=K, 2=V(transposed layout).
__global__ __launch_bounds__(256) void qkv_gemm(
    const short* __restrict__ xb, const short* __restrict__ wqb,
    const short* __restrict__ wkb, const short* __restrict__ wvb,
    const float* __restrict__ bq, const float* __restrict__ bk,
    const float* __restrict__ bvv, short* __restrict__ qo,
    short* __restrict__ ko, short* __restrict__ vto) {
    __shared__ short As[64 * 72];
    __shared__ short Bs[64 * 72];
    const int z = blockIdx.z;
    const short* W = (z == 0) ? wqb : (z == 1) ? wkb : wvb;
    const float* bias = (z == 0) ? bq : (z == 1) ? bk : bvv;
    short* out = (z == 0) ? qo : (z == 1) ? ko : vto;
    const int m0 = blockIdx.x * 64, e0 = blockIdx.y * 64;

    const f32x4 Z = {0.f, 0.f, 0.f, 0.f};
    f32x4 acc[2][2];
#pragma unroll
    for (int i = 0; i < 2; ++i)
#pragma unroll
        for (int j = 0; j < 2; ++j) acc[i][j] = Z;

    gemm_core(xb, W, acc, As, Bs, m0, e0);

    const int lane = threadIdx.x & 63, wid = threadIdx.x >> 6;
    const int c = lane & 15, g = lane >> 4;
    const int wr = (wid >> 1) * 32, wc = (wid & 1) * 32;
#pragma unroll
    for (int nt = 0; nt < 2; ++nt) {
        int e = e0 + wc + nt * 16 + c;
        float bsv = bias[e];
        int h = e >> 6, d = e & 63;
#pragma unroll
        for (int mt = 0; mt < 2; ++mt)
#pragma unroll
            for (int r = 0; r < 4; ++r) {
                int m = m0 + wr + mt * 16 + g * 4 + r;
                int bb = m >> 9, n = m & 511;
                float val = acc[mt][nt][r] + bsv;
                size_t addr;
                if (z == 2) addr = (((size_t)bb * 8 + h) * 64 + d) * 512 + n;
                else        addr = (((size_t)bb * 8 + h) * 512 + n) * 64 + d;
                out[addr] = f2bf(val);
            }
    }
}

// Output projection: fp32 out = ob @ wo^T + bo.
__global__ __launch_bounds__(256) void out_gemm(const short* __restrict__ ob,
                                                const short* __restrict__ wob,
                                                const float* __restrict__ bo,
                                                float* __restrict__ out) {
    __shared__ short As[64 * 72];
    __shared__ short Bs[64 * 72];
    const int m0 = blockIdx.x * 64, e0 = blockIdx.y * 64;
    const f32x4 Z = {0.f, 0.f, 0.f, 0.f};
    f32x4 acc[2][2];
#pragma unroll
    for (int i = 0; i < 2; ++i)
#pragma unroll
        for (int j = 0; j < 2; ++j) acc[i][j] = Z;

    gemm_core(ob, wob, acc, As, Bs, m0, e0);

    const int lane = threadIdx.x & 63, wid = threadIdx.x >> 6;
    const int c = lane & 15, g = lane >> 4;
    const int wr = (wid >> 1) * 32, wc = (wid & 1) * 32;
#pragma unroll
    for (int nt = 0; nt < 2; ++nt) {
        int e = e0 + wc + nt * 16 + c;
        float bsv = bo[e];
#pragma unroll
        for (int mt = 0; mt < 2; ++mt)
#pragma unroll
            for (int r = 0; r < 4; ++r) {
                int m = m0 + wr + mt * 16 + g * 4 + r;
                out[(size_t)m * 512 + e] = acc[mt][nt][r] + bsv;
            }
    }
}

// ---------------------------------------------------------------------------
// MFMA flash attention, software-pipelined. Block = (b, h, 64 q-rows);
// 4 waves, wave-private 16 q-rows; no barriers in the j-loop.
// K-frags and db for iter j+1 prefetched into registers during iter j;
// V loads issued early so softmax covers their latency. Mask preloaded
// into a 32-bit register bitmask. DBB=1: db in bf16 (from ws).
// ---------------------------------------------------------------------------
template <int DBB>
__global__ __launch_bounds__(256) void attn_mfma(
    const short* __restrict__ q, const short* __restrict__ k,
    const short* __restrict__ vt, const float* __restrict__ db,
    const unsigned short* __restrict__ dbb, const int* __restrict__ mask,
    short* __restrict__ o) {
    __shared__ short Pl[4][16 * 72];
    const int tid = threadIdx.x, lane = tid & 63, wid = tid >> 6;
    const int c = lane & 15, g = lane >> 4;
    const int i0 = blockIdx.x * 64;
    const int h = blockIdx.y, b = blockIdx.z;
    const int q0 = i0 + wid * 16;

    const short* qp = q + (((size_t)b * 8 + h) * 512) * 64;
    const short* kp = k + (((size_t)b * 8 + h) * 512) * 64;
    const short* vp = vt + (((size_t)b * 8 + h) * 64) * 512;
    const float* dbpf = db + ((size_t)b * 512 + q0 + g * 4) * 512;
    const unsigned short* dbpb = dbb + ((size_t)b * 512 + q0 + g * 4) * 512;
    const int* mp = mask + b * 512;

    short8 qf0 = *(const short8*)&qp[(q0 + c) * 64 + g * 8];
    short8 qf1 = *(const short8*)&qp[(q0 + c) * 64 + 32 + g * 8];

    // mask bitmask: bit (jidx*4+nt) = mask[jidx*64 + nt*16 + c]
    unsigned mbits = 0;
#pragma unroll
    for (int w = 0; w < 32; ++w) {
        int col = (w >> 2) * 64 + (w & 3) * 16 + c;
        mbits |= (mp[col] != 0 ? 1u : 0u) << w;
    }

    // prefetch K frags + db for j0 = 0
    short8 kf0[4], kf1[4];
#pragma unroll
    for (int nt = 0; nt < 4; ++nt) {
        kf0[nt] = *(const short8*)&kp[(nt * 16 + c) * 64 + g * 8];
        kf1[nt] = *(const short8*)&kp[(nt * 16 + c) * 64 + 32 + g * 8];
    }
    unsigned short dbr[16];
    float dbf[16];
#pragma unroll
    for (int nt = 0; nt < 4; ++nt)
#pragma unroll
        for (int r = 0; r < 4; ++r) {
            if (DBB) dbr[nt * 4 + r] = dbpb[(size_t)r * 512 + nt * 16 + c];
            else     dbf[nt * 4 + r] = dbpf[(size_t)r * 512 + nt * 16 + c];
        }

    float m_run[4], l_run[4], corr[4];
    const f32x4 Z = {0.f, 0.f, 0.f, 0.f};
    f32x4 oacc[4];
#pragma unroll
    for (int r = 0; r < 4; ++r) { m_run[r] = -1e30f; l_run[r] = 0.f; }
#pragma unroll
    for (int dt = 0; dt < 4; ++dt) oacc[dt] = Z;

    short* pl = &Pl[wid][0];

    for (int jidx = 0; jidx < 8; ++jidx) {
        const int j0 = jidx * 64;
        // 1. S = Q K^T from prefetched kf
        f32x4 s[4];
#pragma unroll
        for (int nt = 0; nt < 4; ++nt) {
            f32x4 z = Z;
            z = MFMA16(qf0, kf0[nt], z);
            z = MFMA16(qf1, kf1[nt], z);
            s[nt] = z;
        }
        // 2. prefetch K for next iter (reuse regs; WAR after MFMA)
        if (jidx < 7) {
#pragma unroll
            for (int nt = 0; nt < 4; ++nt) {
                kf0[nt] = *(const short8*)&kp[(j0 + 64 + nt * 16 + c) * 64 + g * 8];
                kf1[nt] = *(const short8*)&kp[(j0 + 64 + nt * 16 + c) * 64 + 32 + g * 8];
            }
        }
        // 3. issue V loads for this iter (used in step 7)
        short8 vf0[4], vf1[4];
#pragma unroll
        for (int dt = 0; dt < 4; ++dt) {
            vf0[dt] = *(const short8*)&vp[(dt * 16 + c) * 512 + j0 + g * 8];
            vf1[dt] = *(const short8*)&vp[(dt * 16 + c) * 512 + j0 + 32 + g * 8];
        }
        // 4. scale + db + clip + mask (db from prefetched regs)
        float sv[4][4];
#pragma unroll
        for (int nt = 0; nt < 4; ++nt) {
            unsigned mk = (mbits >> (jidx * 4 + nt)) & 1u;
#pragma unroll
            for (int r = 0; r < 4; ++r) {
                float dv = DBB ? bf2f(dbr[nt * 4 + r]) : dbf[nt * 4 + r];
                float val = s[nt][r] * 0.125f + dv;
                val = fminf(fmaxf(val, -10.f), 10.f);
                sv[nt][r] = mk ? val : -1e9f;
            }
        }
        // 5. prefetch db for next iter
        if (jidx < 7) {
#pragma unroll
            for (int nt = 0; nt < 4; ++nt)
#pragma unroll
                for (int r = 0; r < 4; ++r) {
                    int col = j0 + 64 + nt * 16 + c;
                    if (DBB) dbr[nt * 4 + r] = dbpb[(size_t)r * 512 + col];
                    else     dbf[nt * 4 + r] = dbpf[(size_t)r * 512 + col];
                }
        }
        // 6. online softmax per q-row r (reduce across the 16 c-lanes)
        float pv[4][4];
#pragma unroll
        for (int r = 0; r < 4; ++r) {
            float mx = fmaxf(fmaxf(sv[0][r], sv[1][r]), fmaxf(sv[2][r], sv[3][r]));
#pragma unroll
            for (int off = 1; off < 16; off <<= 1) mx = fmaxf(mx, __shfl_xor(mx, off));
            float mn = fmaxf(m_run[r], mx);
            corr[r] = __expf(m_run[r] - mn);
            float rs = 0.f;
#pragma unroll
            for (int nt = 0; nt < 4; ++nt) {
                float p = __expf(sv[nt][r] - mn);
                pv[nt][r] = p;
                rs += p;
            }
#pragma unroll
            for (int off = 1; off < 16; off <<= 1) rs += __shfl_xor(rs, off);
            m_run[r] = mn;
            l_run[r] = l_run[r] * corr[r] + rs;
        }
#pragma unroll
        for (int dt = 0; dt < 4; ++dt)
#pragma unroll
            for (int r = 0; r < 4; ++r) oacc[dt][r] *= corr[r];
        // 7. P -> bf16 -> wave-private LDS strip, then PV MFMA
#pragma unroll
        for (int nt = 0; nt < 4; ++nt)
#pragma unroll
            for (int r = 0; r < 4; ++r)
                pl[(g * 4 + r) * 72 + nt * 16 + c] = f2bf(pv[nt][r]);
        asm volatile("s_waitcnt lgkmcnt(0)" ::: "memory");
        __builtin_amdgcn_sched_barrier(0);
        short8 pf0 = *(const short8*)&pl[c * 72 + g * 8];
        short8 pf1 = *(const short8*)&pl[c * 72 + 32 + g * 8];
#pragma unroll
        for (int dt = 0; dt < 4; ++dt) {
            oacc[dt] = MFMA16(pf0, vf0[dt], oacc[dt]);
            oacc[dt] = MFMA16(pf1, vf1[dt], oacc[dt]);
        }
    }
    // epilogue: O /= l, write bf16 [M][E] for the output projection
#pragma unroll
    for (int r = 0; r < 4; ++r) {
        float inv = 1.f / l_run[r];
        int qg = q0 + g * 4 + r;
#pragma unroll
        for (int dt = 0; dt < 4; ++dt)
            o[((size_t)b * 512 + qg) * 512 + h * 64 + dt * 16 + c] =
                f2bf(oacc[dt][r] * inv);
    }
}

extern "C" void kernel_launch(void* const* d_in, const int* in_sizes, int n_in,
                              void* d_out, int out_size, void* d_ws, size_t ws_size,
                              hipStream_t stream) {
    const float* x  = (const float*)d_in[0];
    const float* db = (const float*)d_in[1];
    const int* msk  = (const int*)d_in[2];
    const float* wq = (const float*)d_in[3];
    const float* bq = (const float*)d_in[4];
    const float* wk = (const float*)d_in[5];
    const float* bk = (const float*)d_in[6];
    const float* wv = (const float*)d_in[7];
    const float* bv = (const float*)d_in[8];
    const float* wo = (const float*)d_in[9];
    const float* bo = (const float*)d_in[10];
    float* out = (float*)d_out;

    short* xb  = (short*)d_ws;            // 8192*512
    short* wqb = xb + 4194304;            // 512*512 each
    short* wkb = wqb + 262144;
    short* wvb = wkb + 262144;
    short* wob = wvb + 262144;
    short* qb  = wob + 262144;            // [B,H,N,D] bf16
    short* kb  = qb + 4194304;            // [B,H,N,D]
    short* vtb = kb + 4194304;            // [B,H,D,N]
    short* ob  = vtb + 4194304;           // [M,E] bf16 attention output
    short* dbw = ob + 4194304;            // [B,N,N] bf16 db (optional)

    const size_t need = (size_t)(22020096 + 4194304) * sizeof(short);
    const bool use_dbb = ws_size >= need;

    cvt_kernel<<<use_dbb ? 4608 : 2560, 256, 0, stream>>>(
        x, wq, wk, wv, wo, db, xb, wqb, wkb, wvb, wob, dbw);
    qkv_gemm<<<dim3(128, 8, 3), 256, 0, stream>>>(xb, wqb, wkb, wvb, bq, bk, bv,
                                                  qb, kb, vtb);
    if (use_dbb)
        attn_mfma<1><<<dim3(8, 8, 16), 256, 0, stream>>>(
            qb, kb, vtb, db, (const unsigned short*)dbw, msk, ob);
    else
        attn_mfma<0><<<dim3(8, 8, 16), 256, 0, stream>>>(
            qb, kb, vtb, db, (const unsigned short*)dbw, msk, ob);
    out_gemm<<<dim3(128, 8), 256, 0, stream>>>(ob, wob, bo, out);
}